// Round 16
// baseline (180.201 us; speedup 1.0000x reference)
//
#include <hip/hip_runtime.h>
#include <stdint.h>

typedef __attribute__((ext_vector_type(8))) short short8;
typedef __attribute__((ext_vector_type(4))) short short4v;
typedef __attribute__((ext_vector_type(4))) float float4v;
typedef __attribute__((ext_vector_type(16))) float f32x16;
typedef __attribute__((ext_vector_type(4))) int int4v;
typedef __attribute__((ext_vector_type(2))) int int2v;
typedef __attribute__((ext_vector_type(2))) unsigned int uint2v;

#define DEV __device__ __forceinline__

DEV ushort f2bf(float f){
  uint32_t u = __float_as_uint(f);
  u = (u + 0x7fffu + ((u >> 16) & 1u)) >> 16;
  return (ushort)u;
}
DEV float bf2f(ushort h){
  uint32_t u = ((uint32_t)h) << 16;
  return __uint_as_float(u);
}

DEV void gload16(const void* g, void* l){
  __builtin_amdgcn_global_load_lds((const __attribute__((address_space(1))) void*)g,
                                   (__attribute__((address_space(3))) void*)l, 16, 0, 0);
}

DEV uint32_t cvtpk(float lo, float hi){
  uint32_t d;
  asm("v_cvt_pk_bf16_f32 %0, %1, %2" : "=v"(d) : "v"(lo), "v"(hi));
  return d;
}

DEV uint2v plswap2(uint32_t a, uint32_t b){
  return __builtin_amdgcn_permlane32_swap(a, b, false, false);
}

// ---------------- fused prep: weight transposes + rope table + x cast ----------------
__global__ __launch_bounds__(256) void k_prep(const float* __restrict__ x, const float* __restrict__ Wq,
                                              const float* __restrict__ Wk, const float* __restrict__ Wv,
                                              const float* __restrict__ Wo,
                                              ushort* __restrict__ xb, ushort* __restrict__ wqkvt,
                                              ushort* __restrict__ wot,
                                              float* __restrict__ cost, float* __restrict__ sint,
                                              float qscale){
  __shared__ float tile[32][33];
  const int bid = blockIdx.x;
  if (bid < 10240){
    const float* src; ushort* dst; int N, K, bx, by; float scale;
    if (bid < 4096){ src = Wq; dst = wqkvt; N = 2048; K = 2048; scale = qscale; bx = bid & 63; by = bid >> 6; }
    else if (bid < 5120){ int lb = bid - 4096; src = Wk; dst = wqkvt + (size_t)2048 * 2048; N = 512; K = 2048; scale = 1.f; bx = lb & 15; by = lb >> 4; }
    else if (bid < 6144){ int lb = bid - 5120; src = Wv; dst = wqkvt + (size_t)2560 * 2048; N = 512; K = 2048; scale = 1.f; bx = lb & 15; by = lb >> 4; }
    else { int lb = bid - 6144; src = Wo; dst = wot; N = 2048; K = 2048; scale = 1.f; bx = lb & 63; by = lb >> 6; }
    int c0 = bx * 32, r0 = by * 32;
    int tx = threadIdx.x & 31, ty = threadIdx.x >> 5;
    #pragma unroll
    for (int i = 0; i < 32; i += 8)
      tile[ty + i][tx] = src[(size_t)(r0 + ty + i) * N + (c0 + tx)];
    __syncthreads();
    #pragma unroll
    for (int i = 0; i < 32; i += 8)
      dst[(size_t)(c0 + ty + i) * K + (r0 + tx)] = f2bf(tile[tx][ty + i] * scale);
  } else if (bid < 10496){
    int i = (bid - 10240) * 256 + threadIdx.x;     // 65536
    int s = i >> 5, d = i & 31;
    float inv = powf(10000.0f, -(float)d / 32.0f);
    float ang = (float)s * inv;
    float sv, cv;
    sincosf(ang, &sv, &cv);
    cost[i] = cv;
    sint[i] = sv;
  } else {
    int i = (bid - 10496) * 256 + threadIdx.x;     // 2097152, 4 elems each
    float4v v = *(const float4v*)(x + (size_t)i * 4);
    short4v o;
    o[0] = (short)f2bf(v[0]); o[1] = (short)f2bf(v[1]);
    o[2] = (short)f2bf(v[2]); o[3] = (short)f2bf(v[3]);
    *(short4v*)(xb + (size_t)i * 4) = o;
  }
}

// ---------------- GEMM: single barrier per K-tile (attn-loop pattern) ----------------
template<int BM, int BN, bool OUTF32, int MINW>
__global__ __launch_bounds__(512, MINW) void k_gemm8(const ushort* __restrict__ A, const ushort* __restrict__ Bt,
                                                     void* __restrict__ Cp, int M, int N, int K, int nbx){
  constexpr int WM = BM / 2, WN = BN / 4;
  constexpr int MR = WM / 16, NR = WN / 16, MP = MR / 4;
  constexpr int AISS = BM / 64, BISS = BN / 64;
  constexpr int BUFB = (BM + BN) * 128;            // bytes per K-tile buffer
  __shared__ char lds[2 * BUFB];

  int wg = blockIdx.x;
  int cpx = (int)gridDim.x >> 3;                   // grid divisible by 8
  wg = (wg & 7) * cpx + (wg >> 3);                 // XCD swizzle
  const int bn = wg % nbx, bm = wg / nbx;
  const int tid = threadIdx.x;
  const int w = tid >> 6, l = tid & 63, l15 = l & 15, hi = l >> 4;
  const int wr = w >> 2, wc = w & 3;

  const int r8 = tid >> 3;
  const int ce = ((tid & 7) ^ (r8 & 7)) << 3;      // pre-swizzled source col element
  const ushort* ag = A + (size_t)(bm * BM + r8) * K + ce;
  const ushort* bg = Bt + (size_t)(bn * BN + r8) * K + ce;

  float4v acc[MR][NR];
  #pragma unroll
  for (int a = 0; a < MR; ++a)
    #pragma unroll
    for (int b = 0; b < NR; ++b)
      acc[a][b] = (float4v){0.f, 0.f, 0.f, 0.f};

  auto stage = [&](int kt, int buf){
    char* ab = lds + buf * BUFB;
    char* bb = ab + BM * 128;
    #pragma unroll
    for (int i = 0; i < AISS; ++i)
      gload16(ag + (size_t)(i * 64) * K + kt * 64, ab + i * 8192 + tid * 16);
    #pragma unroll
    for (int i = 0; i < BISS; ++i)
      gload16(bg + (size_t)(i * 64) * K + kt * 64, bb + i * 8192 + tid * 16);
  };
  auto lda = [&](const char* ab, int mf, int kk)->short8{
    int row = wr * WM + mf * 16 + l15;
    int a = (row * 128 + kk * 64 + hi * 16) ^ ((row & 7) << 4);
    return *(const short8*)(ab + a);
  };
  auto ldb = [&](const char* bb, int nf, int kk)->short8{
    int row = wc * WN + nf * 16 + l15;
    int a = (row * 128 + kk * 64 + hi * 16) ^ ((row & 7) << 4);
    return *(const short8*)(bb + a);
  };

  const int nkt = K >> 6;
  stage(0, 0);
  for (int t = 0; t < nkt; ++t){
    asm volatile("s_waitcnt vmcnt(0)" ::: "memory");   // own stage(t) landed
    __builtin_amdgcn_s_barrier();                      // all landed; prior readers done
    __builtin_amdgcn_sched_barrier(0);
    if (t + 1 < nkt) stage(t + 1, (t + 1) & 1);        // safe: post-barrier

    const char* ab = lds + (t & 1) * BUFB;
    const char* bb = ab + BM * 128;
    short8 bfr[NR][2];
    #pragma unroll
    for (int nf = 0; nf < NR; ++nf){ bfr[nf][0] = ldb(bb, nf, 0); bfr[nf][1] = ldb(bb, nf, 1); }
    short8 af[MP][2];
    #pragma unroll
    for (int ml = 0; ml < MP; ++ml){ af[ml][0] = lda(ab, ml, 0); af[ml][1] = lda(ab, ml, 1); }

    #pragma unroll
    for (int p = 0; p < 4; ++p){
      asm volatile("s_waitcnt lgkmcnt(0)" ::: "memory");
      __builtin_amdgcn_sched_barrier(0);
      __builtin_amdgcn_s_setprio(1);
      #pragma unroll
      for (int ml = 0; ml < MP; ++ml)
        #pragma unroll
        for (int nf = 0; nf < NR; ++nf){
          const int mf = p * MP + ml;
          acc[mf][nf] = __builtin_amdgcn_mfma_f32_16x16x32_bf16(af[ml][0], bfr[nf][0], acc[mf][nf], 0, 0, 0);
          acc[mf][nf] = __builtin_amdgcn_mfma_f32_16x16x32_bf16(af[ml][1], bfr[nf][1], acc[mf][nf], 0, 0, 0);
        }
      __builtin_amdgcn_s_setprio(0);
      __builtin_amdgcn_sched_barrier(0);
      if (p < 3){
        #pragma unroll
        for (int ml = 0; ml < MP; ++ml){
          af[ml][0] = lda(ab, (p + 1) * MP + ml, 0);
          af[ml][1] = lda(ab, (p + 1) * MP + ml, 1);
        }
      }
    }
  }

  #pragma unroll
  for (int mf = 0; mf < MR; ++mf){
    int row0 = bm * BM + wr * WM + mf * 16 + hi * 4;
    #pragma unroll
    for (int nf = 0; nf < NR; ++nf){
      int col = bn * BN + wc * WN + nf * 16 + l15;
      #pragma unroll
      for (int reg = 0; reg < 4; ++reg){
        size_t idx = (size_t)(row0 + reg) * N + col;
        if constexpr (OUTF32) ((float*)Cp)[idx] = acc[mf][nf][reg];
        else                  ((ushort*)Cp)[idx] = f2bf(acc[mf][nf][reg]);
      }
    }
  }
}

// ---------------- fused RoPE (in-place on q/k cols) + build Vt ----------------
__global__ __launch_bounds__(256) void k_rope_vt(ushort* __restrict__ qkv, const float* __restrict__ cost,
                                                 const float* __restrict__ sint, ushort* __restrict__ vt){
  __shared__ ushort tile[64][72];
  const int bid = blockIdx.x;
  if (bid < 5120){
    int t = bid * 256 + threadIdx.x;             // 4096 * 320 = 1310720
    int row = t / 320;
    int rem = t - row * 320;
    int head = rem >> 3, d0 = (rem & 7) * 4;     // head 0..39 covers q(0..31) + k(32..39)
    int s = row & 2047;
    ushort* p = qkv + (size_t)row * 3072 + head * 64 + d0;
    short4v a = *(short4v*)p;
    short4v b = *(short4v*)(p + 32);
    float4v c  = *(const float4v*)(cost + s * 32 + d0);
    float4v sn = *(const float4v*)(sint + s * 32 + d0);
    short4v na, nb;
    #pragma unroll
    for (int j = 0; j < 4; ++j){
      float x1 = bf2f((ushort)a[j]), x2 = bf2f((ushort)b[j]);
      na[j] = (short)f2bf(x1 * c[j] - x2 * sn[j]);
      nb[j] = (short)f2bf(x2 * c[j] + x1 * sn[j]);
    }
    *(short4v*)p = na;
    *(short4v*)(p + 32) = nb;
  } else {
    int lb = bid - 5120;                          // 512
    int g = lb >> 5, st = lb & 31;                // g = b*8+hk, st = s-tile
    int b = g >> 3, hk = g & 7;
    const ushort* src = qkv + (size_t)(b * 2048 + st * 64) * 3072 + 2560 + hk * 64;
    int tid = threadIdx.x;
    #pragma unroll
    for (int i = 0; i < 2; ++i){
      int r = i * 32 + (tid >> 3), c8 = (tid & 7) * 8;
      short8 v = *(const short8*)(src + (size_t)r * 3072 + c8);
      #pragma unroll
      for (int j = 0; j < 8; ++j) tile[r][c8 + j] = (ushort)v[j];
    }
    __syncthreads();
    ushort* dst = vt + (size_t)g * 64 * 2048 + st * 64;
    #pragma unroll
    for (int i = 0; i < 2; ++i){
      int d = i * 32 + (tid >> 3), s8 = (tid & 7) * 8;
      short8 ov;
      #pragma unroll
      for (int j = 0; j < 8; ++j) ov[j] = (short)tile[s8 + j][d];
      *(short8*)(dst + (size_t)d * 2048 + s8) = ov;
    }
  }
}

// ---------------- causal GQA flash attention v12: queue-balanced 64-row blocks ----------------
// k_attn10 wave-body verbatim; block = 128 thr (2 waves), 64 q-rows (qt 0..31).
// Grid 2048 > residency capacity 1280 (32KB LDS -> 5 blocks/CU): the HW dispatch
// queue backfills finished blocks, heavy-first (qt descending) ordering makes
// the queue the load balancer. No partials, no outer loops, no new arithmetic.
__global__ __launch_bounds__(128) void k_attn12(const ushort* __restrict__ qkv, const ushort* __restrict__ vt,
                                                ushort* __restrict__ att){
  __shared__ __align__(16) char lds[2][16384];    // per buf: K [64][128B] | V [64][128B]
  const int id = blockIdx.x;                      // 2048
  const int xcd = id & 7;
  const int lid = id >> 3;                        // 0..255
  const int qt = 31 - (lid >> 3);                 // heavy first
  const int gh = (lid >> 2) & 1;
  const int hloc = lid & 3;
  const int gidx = xcd * 2 + gh;                  // b*8+hk
  const int b = gidx >> 3, hk = gidx & 7;
  const int h = hk * 4 + hloc;
  const int tid = threadIdx.x;                    // 0..127
  const int w = tid >> 6, l = tid & 63, ql = l & 31, g = l >> 5;
  const int qw = qt * 64 + w * 32;                // wave's first q row
  const int diag_t = (qw + 31) >> 6;
  const int nt = qt + 1;
  const int swz = (ql & 7) << 4;

  short8 qf[4];
  {
    const ushort* qbase = qkv + (size_t)(b * 2048 + qw + ql) * 3072 + h * 64 + g * 8;
    #pragma unroll
    for (int ds = 0; ds < 4; ++ds) qf[ds] = *(const short8*)(qbase + ds * 16);
  }
  short8 onesf;
  #pragma unroll
  for (int i = 0; i < 8; ++i) onesf[i] = (short)0x3F80;   // bf16 1.0

  f32x16 o0, o1, ladd;
  #pragma unroll
  for (int r = 0; r < 16; ++r){ o0[r] = 0.f; o1[r] = 0.f; ladd[r] = 0.f; }

  const int srow = tid >> 3;                      // 0..15
  const int ce = ((tid & 7) ^ (srow & 7)) << 3;   // pre-swizzled source col
  const ushort* kg = qkv + (size_t)(b * 2048 + srow) * 3072 + 2048 + hk * 64 + ce;
  const ushort* vg = vt + (size_t)gidx * 64 * 2048 + (size_t)srow * 2048 + ce;

  auto stage = [&](int t, int buf){
    char* lb = lds[buf];
    #pragma unroll
    for (int i = 0; i < 4; ++i)
      gload16(kg + (size_t)(t * 64 + i * 16) * 3072, lb + i * 2048 + tid * 16);
    #pragma unroll
    for (int i = 0; i < 4; ++i)
      gload16(vg + (size_t)(i * 16) * 2048 + t * 64, lb + 8192 + i * 2048 + tid * 16);
  };

  stage(0, 0);
  for (int t = 0; t < nt; ++t){
    asm volatile("s_waitcnt vmcnt(0)" ::: "memory");   // own stage(t) complete
    __builtin_amdgcn_s_barrier();                      // both waves' stage(t) complete
    __builtin_amdgcn_sched_barrier(0);
    if (t + 1 < nt) stage(t + 1, (t + 1) & 1);         // issue next tile (safe: post-barrier)

    if (t <= diag_t){
      const char* Kb = lds[t & 1];
      const char* Vb = Kb + 8192;

      // ---- QK^T -> S^T ----
      f32x16 sa0, sa1;
      #pragma unroll
      for (int r = 0; r < 16; ++r){ sa0[r] = 0.f; sa1[r] = 0.f; }
      __builtin_amdgcn_s_setprio(1);
      #pragma unroll
      for (int ds = 0; ds < 4; ++ds){
        int cb = (ds * 32 + g * 16) ^ swz;
        short8 k0 = *(const short8*)(Kb + ql * 128 + cb);
        short8 k1 = *(const short8*)(Kb + (32 + ql) * 128 + cb);
        sa0 = __builtin_amdgcn_mfma_f32_32x32x16_bf16(k0, qf[ds], sa0, 0, 0, 0);
        sa1 = __builtin_amdgcn_mfma_f32_32x32x16_bf16(k1, qf[ds], sa1, 0, 0, 0);
      }
      __builtin_amdgcn_s_setprio(0);

      // ---- causal mask (diagonal tile only) ----
      if (t == diag_t){
        int thr = qw + ql - t * 64;
        #pragma unroll
        for (int r = 0; r < 16; ++r){
          int kl = (r & 3) + 8 * (r >> 2) + 4 * g;
          sa0[r] = (kl > thr) ? -3e38f : sa0[r];
          sa1[r] = (kl + 32 > thr) ? -3e38f : sa1[r];
        }
      }

      // ---- exp2 (maxless) + pack ----
      uint32_t wds[2][8];
      #pragma unroll
      for (int u = 0; u < 8; ++u){
        float a0 = __builtin_amdgcn_exp2f(sa0[2 * u]);
        float a1 = __builtin_amdgcn_exp2f(sa0[2 * u + 1]);
        wds[0][u] = cvtpk(a0, a1);
        float b0 = __builtin_amdgcn_exp2f(sa1[2 * u]);
        float b1 = __builtin_amdgcn_exp2f(sa1[2 * u + 1]);
        wds[1][u] = cvtpk(b0, b1);
      }

      // ---- PV + l-from-MFMA ----
      __builtin_amdgcn_s_setprio(1);
      #pragma unroll
      for (int ks = 0; ks < 4; ++ks){
        const int s2 = ks >> 1, c4 = (ks & 1) * 4;
        uint2v e0 = plswap2(wds[s2][c4 + 0], wds[s2][c4 + 2]);
        uint2v e1 = plswap2(wds[s2][c4 + 1], wds[s2][c4 + 3]);
        union { int4v w4; short8 s8; } pb;
        pb.w4[0] = (int)e0[0]; pb.w4[1] = (int)e1[0];
        pb.w4[2] = (int)e0[1]; pb.w4[3] = (int)e1[1];
        int cb = (ks * 32 + g * 16) ^ swz;
        short8 v0 = *(const short8*)(Vb + ql * 128 + cb);
        short8 v1 = *(const short8*)(Vb + (32 + ql) * 128 + cb);
        o0 = __builtin_amdgcn_mfma_f32_32x32x16_bf16(v0, pb.s8, o0, 0, 0, 0);
        o1 = __builtin_amdgcn_mfma_f32_32x32x16_bf16(v1, pb.s8, o1, 0, 0, 0);
        ladd = __builtin_amdgcn_mfma_f32_32x32x16_bf16(onesf, pb.s8, ladd, 0, 0, 0);
      }
      __builtin_amdgcn_s_setprio(0);
    }
  }

  // ---- epilogue: l = ladd[0] (all rows identical, spans all kv), store O^T ----
  float invl = 1.0f / ladd[0];
  ushort* ob = att + (size_t)(b * 2048 + qw + ql) * 2048 + h * 64;
  #pragma unroll
  for (int dm = 0; dm < 2; ++dm){
    #pragma unroll
    for (int rg = 0; rg < 4; ++rg){
      float f0 = (dm ? o1[4 * rg + 0] : o0[4 * rg + 0]) * invl;
      float f1 = (dm ? o1[4 * rg + 1] : o0[4 * rg + 1]) * invl;
      float f2 = (dm ? o1[4 * rg + 2] : o0[4 * rg + 2]) * invl;
      float f3 = (dm ? o1[4 * rg + 3] : o0[4 * rg + 3]) * invl;
      int2v wv;
      wv[0] = (int)cvtpk(f0, f1);
      wv[1] = (int)cvtpk(f2, f3);
      int d0 = dm * 32 + 8 * rg + 4 * g;
      *(int2v*)(ob + d0) = wv;
    }
  }
}

// ---------------- launch ----------------
extern "C" void kernel_launch(void* const* d_in, const int* in_sizes, int n_in,
                              void* d_out, int out_size, void* d_ws, size_t ws_size,
                              hipStream_t stream) {
  const float* x  = (const float*)d_in[0];
  // d_in[1] = mask (causal tril; handled analytically)
  const float* Wq = (const float*)d_in[2];
  const float* Wk = (const float*)d_in[3];
  const float* Wv = (const float*)d_in[4];
  const float* Wo = (const float*)d_in[5];

  char* ws = (char*)d_ws;
  ushort* xb    = (ushort*)(ws);                       // [4096][2048] bf16    16 MiB
  ushort* wqkvt = (ushort*)(ws + (16u << 20));         // [3072][2048] bf16    12 MiB
  ushort* wot   = (ushort*)(ws + (28u << 20));         // [2048][2048] bf16     8 MiB
  ushort* qkv   = (ushort*)(ws + (36u << 20));         // [4096][3072] bf16    24 MiB
  ushort* att   = (ushort*)(ws + (60u << 20));         // [4096][2048] bf16    16 MiB
  ushort* vt    = (ushort*)(ws + (76u << 20));         // [16][64][2048] bf16   4 MiB
  float*  cost  = (float*)(ws + (80u << 20));          // [2048][32] f32
  float*  sint  = (float*)(ws + (80u << 20) + 262144);

  const float qscale = 0.125f * 1.4426950408889634f;   // HD^-0.5 * log2(e), folded into Wq

  k_prep<<<18688, 256, 0, stream>>>(x, Wq, Wk, Wv, Wo, xb, wqkvt, wot, cost, sint, qscale);
  k_gemm8<128, 192, false, 4><<<512, 512, 0, stream>>>(xb, wqkvt, qkv, 4096, 3072, 2048, 16);
  k_rope_vt<<<5632, 256, 0, stream>>>(qkv, cost, sint, vt);
  k_attn12<<<2048, 128, 0, stream>>>(qkv, vt, att);
  k_gemm8<128, 128, true, 4><<<512, 512, 0, stream>>>(att, wot, d_out, 4096, 2048, 2048, 16);
}

// Round 17
// 163.904 us; speedup vs baseline: 1.0994x; 1.0994x over previous
//
#include <hip/hip_runtime.h>
#include <stdint.h>

typedef __attribute__((ext_vector_type(8))) short short8;
typedef __attribute__((ext_vector_type(4))) short short4v;
typedef __attribute__((ext_vector_type(4))) float float4v;
typedef __attribute__((ext_vector_type(16))) float f32x16;
typedef __attribute__((ext_vector_type(4))) int int4v;
typedef __attribute__((ext_vector_type(2))) int int2v;
typedef __attribute__((ext_vector_type(2))) unsigned int uint2v;

#define DEV __device__ __forceinline__

DEV ushort f2bf(float f){
  uint32_t u = __float_as_uint(f);
  u = (u + 0x7fffu + ((u >> 16) & 1u)) >> 16;
  return (ushort)u;
}
DEV float bf2f(ushort h){
  uint32_t u = ((uint32_t)h) << 16;
  return __uint_as_float(u);
}

DEV void gload16(const void* g, void* l){
  __builtin_amdgcn_global_load_lds((const __attribute__((address_space(1))) void*)g,
                                   (__attribute__((address_space(3))) void*)l, 16, 0, 0);
}

DEV uint32_t cvtpk(float lo, float hi){
  uint32_t d;
  asm("v_cvt_pk_bf16_f32 %0, %1, %2" : "=v"(d) : "v"(lo), "v"(hi));
  return d;
}

DEV uint2v plswap2(uint32_t a, uint32_t b){
  return __builtin_amdgcn_permlane32_swap(a, b, false, false);
}

// ---------------- fused prep: weight transposes + rope table + x cast ----------------
__global__ __launch_bounds__(256) void k_prep(const float* __restrict__ x, const float* __restrict__ Wq,
                                              const float* __restrict__ Wk, const float* __restrict__ Wv,
                                              const float* __restrict__ Wo,
                                              ushort* __restrict__ xb, ushort* __restrict__ wqkvt,
                                              ushort* __restrict__ wot,
                                              float* __restrict__ cost, float* __restrict__ sint,
                                              float qscale){
  __shared__ float tile[32][33];
  const int bid = blockIdx.x;
  if (bid < 10240){
    const float* src; ushort* dst; int N, K, bx, by; float scale;
    if (bid < 4096){ src = Wq; dst = wqkvt; N = 2048; K = 2048; scale = qscale; bx = bid & 63; by = bid >> 6; }
    else if (bid < 5120){ int lb = bid - 4096; src = Wk; dst = wqkvt + (size_t)2048 * 2048; N = 512; K = 2048; scale = 1.f; bx = lb & 15; by = lb >> 4; }
    else if (bid < 6144){ int lb = bid - 5120; src = Wv; dst = wqkvt + (size_t)2560 * 2048; N = 512; K = 2048; scale = 1.f; bx = lb & 15; by = lb >> 4; }
    else { int lb = bid - 6144; src = Wo; dst = wot; N = 2048; K = 2048; scale = 1.f; bx = lb & 63; by = lb >> 6; }
    int c0 = bx * 32, r0 = by * 32;
    int tx = threadIdx.x & 31, ty = threadIdx.x >> 5;
    #pragma unroll
    for (int i = 0; i < 32; i += 8)
      tile[ty + i][tx] = src[(size_t)(r0 + ty + i) * N + (c0 + tx)];
    __syncthreads();
    #pragma unroll
    for (int i = 0; i < 32; i += 8)
      dst[(size_t)(c0 + ty + i) * K + (r0 + tx)] = f2bf(tile[tx][ty + i] * scale);
  } else if (bid < 10496){
    int i = (bid - 10240) * 256 + threadIdx.x;     // 65536
    int s = i >> 5, d = i & 31;
    float inv = powf(10000.0f, -(float)d / 32.0f);
    float ang = (float)s * inv;
    float sv, cv;
    sincosf(ang, &sv, &cv);
    cost[i] = cv;
    sint[i] = sv;
  } else {
    int i = (bid - 10496) * 256 + threadIdx.x;     // 2097152, 4 elems each
    float4v v = *(const float4v*)(x + (size_t)i * 4);
    short4v o;
    o[0] = (short)f2bf(v[0]); o[1] = (short)f2bf(v[1]);
    o[2] = (short)f2bf(v[2]); o[3] = (short)f2bf(v[3]);
    *(short4v*)(xb + (size_t)i * 4) = o;
  }
}

// ---------------- GEMM: single barrier per K-tile (attn-loop pattern) ----------------
template<int BM, int BN, bool OUTF32, int MINW>
__global__ __launch_bounds__(512, MINW) void k_gemm8(const ushort* __restrict__ A, const ushort* __restrict__ Bt,
                                                     void* __restrict__ Cp, int M, int N, int K, int nbx){
  constexpr int WM = BM / 2, WN = BN / 4;
  constexpr int MR = WM / 16, NR = WN / 16, MP = MR / 4;
  constexpr int AISS = BM / 64, BISS = BN / 64;
  constexpr int BUFB = (BM + BN) * 128;            // bytes per K-tile buffer
  __shared__ char lds[2 * BUFB];

  int wg = blockIdx.x;
  int cpx = (int)gridDim.x >> 3;                   // grid divisible by 8
  wg = (wg & 7) * cpx + (wg >> 3);                 // XCD swizzle
  const int bn = wg % nbx, bm = wg / nbx;
  const int tid = threadIdx.x;
  const int w = tid >> 6, l = tid & 63, l15 = l & 15, hi = l >> 4;
  const int wr = w >> 2, wc = w & 3;

  const int r8 = tid >> 3;
  const int ce = ((tid & 7) ^ (r8 & 7)) << 3;      // pre-swizzled source col element
  const ushort* ag = A + (size_t)(bm * BM + r8) * K + ce;
  const ushort* bg = Bt + (size_t)(bn * BN + r8) * K + ce;

  float4v acc[MR][NR];
  #pragma unroll
  for (int a = 0; a < MR; ++a)
    #pragma unroll
    for (int b = 0; b < NR; ++b)
      acc[a][b] = (float4v){0.f, 0.f, 0.f, 0.f};

  auto stage = [&](int kt, int buf){
    char* ab = lds + buf * BUFB;
    char* bb = ab + BM * 128;
    #pragma unroll
    for (int i = 0; i < AISS; ++i)
      gload16(ag + (size_t)(i * 64) * K + kt * 64, ab + i * 8192 + tid * 16);
    #pragma unroll
    for (int i = 0; i < BISS; ++i)
      gload16(bg + (size_t)(i * 64) * K + kt * 64, bb + i * 8192 + tid * 16);
  };
  auto lda = [&](const char* ab, int mf, int kk)->short8{
    int row = wr * WM + mf * 16 + l15;
    int a = (row * 128 + kk * 64 + hi * 16) ^ ((row & 7) << 4);
    return *(const short8*)(ab + a);
  };
  auto ldb = [&](const char* bb, int nf, int kk)->short8{
    int row = wc * WN + nf * 16 + l15;
    int a = (row * 128 + kk * 64 + hi * 16) ^ ((row & 7) << 4);
    return *(const short8*)(bb + a);
  };

  const int nkt = K >> 6;
  stage(0, 0);
  for (int t = 0; t < nkt; ++t){
    asm volatile("s_waitcnt vmcnt(0)" ::: "memory");   // own stage(t) landed
    __builtin_amdgcn_s_barrier();                      // all landed; prior readers done
    __builtin_amdgcn_sched_barrier(0);
    if (t + 1 < nkt) stage(t + 1, (t + 1) & 1);        // safe: post-barrier

    const char* ab = lds + (t & 1) * BUFB;
    const char* bb = ab + BM * 128;
    short8 bfr[NR][2];
    #pragma unroll
    for (int nf = 0; nf < NR; ++nf){ bfr[nf][0] = ldb(bb, nf, 0); bfr[nf][1] = ldb(bb, nf, 1); }
    short8 af[MP][2];
    #pragma unroll
    for (int ml = 0; ml < MP; ++ml){ af[ml][0] = lda(ab, ml, 0); af[ml][1] = lda(ab, ml, 1); }

    #pragma unroll
    for (int p = 0; p < 4; ++p){
      asm volatile("s_waitcnt lgkmcnt(0)" ::: "memory");
      __builtin_amdgcn_sched_barrier(0);
      __builtin_amdgcn_s_setprio(1);
      #pragma unroll
      for (int ml = 0; ml < MP; ++ml)
        #pragma unroll
        for (int nf = 0; nf < NR; ++nf){
          const int mf = p * MP + ml;
          acc[mf][nf] = __builtin_amdgcn_mfma_f32_16x16x32_bf16(af[ml][0], bfr[nf][0], acc[mf][nf], 0, 0, 0);
          acc[mf][nf] = __builtin_amdgcn_mfma_f32_16x16x32_bf16(af[ml][1], bfr[nf][1], acc[mf][nf], 0, 0, 0);
        }
      __builtin_amdgcn_s_setprio(0);
      __builtin_amdgcn_sched_barrier(0);
      if (p < 3){
        #pragma unroll
        for (int ml = 0; ml < MP; ++ml){
          af[ml][0] = lda(ab, (p + 1) * MP + ml, 0);
          af[ml][1] = lda(ab, (p + 1) * MP + ml, 1);
        }
      }
    }
  }

  #pragma unroll
  for (int mf = 0; mf < MR; ++mf){
    int row0 = bm * BM + wr * WM + mf * 16 + hi * 4;
    #pragma unroll
    for (int nf = 0; nf < NR; ++nf){
      int col = bn * BN + wc * WN + nf * 16 + l15;
      #pragma unroll
      for (int reg = 0; reg < 4; ++reg){
        size_t idx = (size_t)(row0 + reg) * N + col;
        if constexpr (OUTF32) ((float*)Cp)[idx] = acc[mf][nf][reg];
        else                  ((ushort*)Cp)[idx] = f2bf(acc[mf][nf][reg]);
      }
    }
  }
}

// ---------------- fused RoPE (in-place on q/k cols) + build Vt ----------------
__global__ __launch_bounds__(256) void k_rope_vt(ushort* __restrict__ qkv, const float* __restrict__ cost,
                                                 const float* __restrict__ sint, ushort* __restrict__ vt){
  __shared__ ushort tile[64][72];
  const int bid = blockIdx.x;
  if (bid < 5120){
    int t = bid * 256 + threadIdx.x;             // 4096 * 320 = 1310720
    int row = t / 320;
    int rem = t - row * 320;
    int head = rem >> 3, d0 = (rem & 7) * 4;     // head 0..39 covers q(0..31) + k(32..39)
    int s = row & 2047;
    ushort* p = qkv + (size_t)row * 3072 + head * 64 + d0;
    short4v a = *(short4v*)p;
    short4v b = *(short4v*)(p + 32);
    float4v c  = *(const float4v*)(cost + s * 32 + d0);
    float4v sn = *(const float4v*)(sint + s * 32 + d0);
    short4v na, nb;
    #pragma unroll
    for (int j = 0; j < 4; ++j){
      float x1 = bf2f((ushort)a[j]), x2 = bf2f((ushort)b[j]);
      na[j] = (short)f2bf(x1 * c[j] - x2 * sn[j]);
      nb[j] = (short)f2bf(x2 * c[j] + x1 * sn[j]);
    }
    *(short4v*)p = na;
    *(short4v*)(p + 32) = nb;
  } else {
    int lb = bid - 5120;                          // 512
    int g = lb >> 5, st = lb & 31;                // g = b*8+hk, st = s-tile
    int b = g >> 3, hk = g & 7;
    const ushort* src = qkv + (size_t)(b * 2048 + st * 64) * 3072 + 2560 + hk * 64;
    int tid = threadIdx.x;
    #pragma unroll
    for (int i = 0; i < 2; ++i){
      int r = i * 32 + (tid >> 3), c8 = (tid & 7) * 8;
      short8 v = *(const short8*)(src + (size_t)r * 3072 + c8);
      #pragma unroll
      for (int j = 0; j < 8; ++j) tile[r][c8 + j] = (ushort)v[j];
    }
    __syncthreads();
    ushort* dst = vt + (size_t)g * 64 * 2048 + st * 64;
    #pragma unroll
    for (int i = 0; i < 2; ++i){
      int d = i * 32 + (tid >> 3), s8 = (tid & 7) * 8;
      short8 ov;
      #pragma unroll
      for (int j = 0; j < 8; ++j) ov[j] = (short)tile[s8 + j][d];
      *(short8*)(dst + (size_t)d * 2048 + s8) = ov;
    }
  }
}

// ---------------- causal GQA flash attention v10: CU-complementary qb placement ----------------
// (final configuration — measured 57.0 us, VGPR 76, no spill)
__global__ __launch_bounds__(256) void k_attn10(const ushort* __restrict__ qkv, const ushort* __restrict__ vt,
                                                ushort* __restrict__ att){
  __shared__ __align__(16) char lds[2][16384];    // per buf: K [64][128B] | V [64][128B]
  const int id = blockIdx.x;                      // 1024
  const int xcd = id & 7;
  const int lid = id >> 3;                        // 0..127
  const int cuL = lid & 31;                       // CU within XCD (dispatch model)
  const int layer = lid >> 5;                     // 0..3
  const int gidx = xcd * 2 + (cuL >> 4);          // b*8+hk, fixed per CU-half
  const int b = gidx >> 3, hk = gidx & 7;
  const int hloc = cuL & 3;
  const int m = (cuL >> 2) & 3;
  const int qb = (layer == 0) ? (15 - m) : (layer == 1) ? m : (layer == 2) ? (11 - m) : (4 + m);
  const int h = hk * 4 + hloc;
  const int tid = threadIdx.x;
  const int w = tid >> 6, l = tid & 63, ql = l & 31, g = l >> 5;
  const int qw = qb * 128 + w * 32;               // wave's first q row
  const int diag_t = (qw + 31) >> 6;
  const int swz = (ql & 7) << 4;

  short8 qf[4];
  {
    const ushort* qbase = qkv + (size_t)(b * 2048 + qw + ql) * 3072 + h * 64 + g * 8;
    #pragma unroll
    for (int ds = 0; ds < 4; ++ds) qf[ds] = *(const short8*)(qbase + ds * 16);
  }
  short8 onesf;
  #pragma unroll
  for (int i = 0; i < 8; ++i) onesf[i] = (short)0x3F80;   // bf16 1.0

  f32x16 o0, o1, ladd;
  #pragma unroll
  for (int r = 0; r < 16; ++r){ o0[r] = 0.f; o1[r] = 0.f; ladd[r] = 0.f; }

  const int srow = tid >> 3;
  const int ce = ((tid & 7) ^ (srow & 7)) << 3;
  const ushort* kg = qkv + (size_t)(b * 2048 + srow) * 3072 + 2048 + hk * 64 + ce;
  const ushort* vg = vt + (size_t)gidx * 64 * 2048 + (size_t)srow * 2048 + ce;
  const int nt = qb * 2 + 2;

  auto stage = [&](int t, int buf){
    char* lb = lds[buf];
    #pragma unroll
    for (int i = 0; i < 2; ++i)
      gload16(kg + (size_t)(t * 64 + i * 32) * 3072, lb + i * 4096 + tid * 16);
    #pragma unroll
    for (int i = 0; i < 2; ++i)
      gload16(vg + (size_t)(i * 32) * 2048 + t * 64, lb + 8192 + i * 4096 + tid * 16);
  };

  stage(0, 0);
  for (int t = 0; t < nt; ++t){
    asm volatile("s_waitcnt vmcnt(0)" ::: "memory");   // own stage(t) complete
    __builtin_amdgcn_s_barrier();                      // all waves' stage(t) complete
    __builtin_amdgcn_sched_barrier(0);
    if (t + 1 < nt) stage(t + 1, (t + 1) & 1);         // issue next tile (safe: post-barrier)

    if (t <= diag_t){
      const char* Kb = lds[t & 1];
      const char* Vb = Kb + 8192;

      // ---- QK^T -> S^T ----
      f32x16 sa0, sa1;
      #pragma unroll
      for (int r = 0; r < 16; ++r){ sa0[r] = 0.f; sa1[r] = 0.f; }
      __builtin_amdgcn_s_setprio(1);
      #pragma unroll
      for (int ds = 0; ds < 4; ++ds){
        int cb = (ds * 32 + g * 16) ^ swz;
        short8 k0 = *(const short8*)(Kb + ql * 128 + cb);
        short8 k1 = *(const short8*)(Kb + (32 + ql) * 128 + cb);
        sa0 = __builtin_amdgcn_mfma_f32_32x32x16_bf16(k0, qf[ds], sa0, 0, 0, 0);
        sa1 = __builtin_amdgcn_mfma_f32_32x32x16_bf16(k1, qf[ds], sa1, 0, 0, 0);
      }
      __builtin_amdgcn_s_setprio(0);

      // ---- causal mask (diagonal tile only) ----
      if (t == diag_t){
        int thr = qw + ql - t * 64;
        #pragma unroll
        for (int r = 0; r < 16; ++r){
          int kl = (r & 3) + 8 * (r >> 2) + 4 * g;
          sa0[r] = (kl > thr) ? -3e38f : sa0[r];
          sa1[r] = (kl + 32 > thr) ? -3e38f : sa1[r];
        }
      }

      // ---- exp2 (maxless) + pack ----
      uint32_t wds[2][8];
      #pragma unroll
      for (int u = 0; u < 8; ++u){
        float a0 = __builtin_amdgcn_exp2f(sa0[2 * u]);
        float a1 = __builtin_amdgcn_exp2f(sa0[2 * u + 1]);
        wds[0][u] = cvtpk(a0, a1);
        float b0 = __builtin_amdgcn_exp2f(sa1[2 * u]);
        float b1 = __builtin_amdgcn_exp2f(sa1[2 * u + 1]);
        wds[1][u] = cvtpk(b0, b1);
      }

      // ---- PV + l-from-MFMA ----
      __builtin_amdgcn_s_setprio(1);
      #pragma unroll
      for (int ks = 0; ks < 4; ++ks){
        const int s2 = ks >> 1, c4 = (ks & 1) * 4;
        uint2v e0 = plswap2(wds[s2][c4 + 0], wds[s2][c4 + 2]);
        uint2v e1 = plswap2(wds[s2][c4 + 1], wds[s2][c4 + 3]);
        union { int4v w4; short8 s8; } pb;
        pb.w4[0] = (int)e0[0]; pb.w4[1] = (int)e1[0];
        pb.w4[2] = (int)e0[1]; pb.w4[3] = (int)e1[1];
        int cb = (ks * 32 + g * 16) ^ swz;
        short8 v0 = *(const short8*)(Vb + ql * 128 + cb);
        short8 v1 = *(const short8*)(Vb + (32 + ql) * 128 + cb);
        o0 = __builtin_amdgcn_mfma_f32_32x32x16_bf16(v0, pb.s8, o0, 0, 0, 0);
        o1 = __builtin_amdgcn_mfma_f32_32x32x16_bf16(v1, pb.s8, o1, 0, 0, 0);
        ladd = __builtin_amdgcn_mfma_f32_32x32x16_bf16(onesf, pb.s8, ladd, 0, 0, 0);
      }
      __builtin_amdgcn_s_setprio(0);
    }
  }

  // ---- epilogue: l = ladd[0] (all rows identical, spans all kv), store O^T ----
  float invl = 1.0f / ladd[0];
  ushort* ob = att + (size_t)(b * 2048 + qw + ql) * 2048 + h * 64;
  #pragma unroll
  for (int dm = 0; dm < 2; ++dm){
    #pragma unroll
    for (int rg = 0; rg < 4; ++rg){
      float f0 = (dm ? o1[4 * rg + 0] : o0[4 * rg + 0]) * invl;
      float f1 = (dm ? o1[4 * rg + 1] : o0[4 * rg + 1]) * invl;
      float f2 = (dm ? o1[4 * rg + 2] : o0[4 * rg + 2]) * invl;
      float f3 = (dm ? o1[4 * rg + 3] : o0[4 * rg + 3]) * invl;
      int2v wv;
      wv[0] = (int)cvtpk(f0, f1);
      wv[1] = (int)cvtpk(f2, f3);
      int d0 = dm * 32 + 8 * rg + 4 * g;
      *(int2v*)(ob + d0) = wv;
    }
  }
}

// ---------------- launch ----------------
extern "C" void kernel_launch(void* const* d_in, const int* in_sizes, int n_in,
                              void* d_out, int out_size, void* d_ws, size_t ws_size,
                              hipStream_t stream) {
  const float* x  = (const float*)d_in[0];
  // d_in[1] = mask (causal tril; handled analytically)
  const float* Wq = (const float*)d_in[2];
  const float* Wk = (const float*)d_in[3];
  const float* Wv = (const float*)d_in[4];
  const float* Wo = (const float*)d_in[5];

  char* ws = (char*)d_ws;
  ushort* xb    = (ushort*)(ws);                       // [4096][2048] bf16    16 MiB
  ushort* wqkvt = (ushort*)(ws + (16u << 20));         // [3072][2048] bf16    12 MiB
  ushort* wot   = (ushort*)(ws + (28u << 20));         // [2048][2048] bf16     8 MiB
  ushort* qkv   = (ushort*)(ws + (36u << 20));         // [4096][3072] bf16    24 MiB
  ushort* att   = (ushort*)(ws + (60u << 20));         // [4096][2048] bf16    16 MiB
  ushort* vt    = (ushort*)(ws + (76u << 20));         // [16][64][2048] bf16   4 MiB
  float*  cost  = (float*)(ws + (80u << 20));          // [2048][32] f32
  float*  sint  = (float*)(ws + (80u << 20) + 262144);

  const float qscale = 0.125f * 1.4426950408889634f;   // HD^-0.5 * log2(e), folded into Wq

  k_prep<<<18688, 256, 0, stream>>>(x, Wq, Wk, Wv, Wo, xb, wqkvt, wot, cost, sint, qscale);
  k_gemm8<128, 192, false, 4><<<512, 512, 0, stream>>>(xb, wqkvt, qkv, 4096, 3072, 2048, 16);
  k_rope_vt<<<5632, 256, 0, stream>>>(qkv, cost, sint, vt);
  k_attn10<<<1024, 256, 0, stream>>>(qkv, vt, att);
  k_gemm8<128, 128, true, 4><<<512, 512, 0, stream>>>(att, wot, d_out, 4096, 2048, 2048, 16);
}